// Round 11
// baseline (248.829 us; speedup 1.0000x reference)
//
#include <hip/hip_runtime.h>

typedef unsigned short ushort_t;
typedef __attribute__((ext_vector_type(8))) __bf16 bf16x8;
typedef __attribute__((ext_vector_type(4))) float f32x4;
typedef __attribute__((ext_vector_type(4))) int i32x4;
typedef __attribute__((ext_vector_type(4))) unsigned short u16x4;

#define BN_EPS 1e-5f
#define EPAD 136  // epilogue [p][c] c-stride (272B row, 16B-aligned)

// counted waitcnt via inline asm (no builtin); memory clobber pins VMEM/LDS ops.
// barriers use the builtin (scheduler-aware, does NOT force a vmcnt drain).
#define BAR()    __builtin_amdgcn_s_barrier()
#define VMCNT8() asm volatile("s_waitcnt vmcnt(8)" ::: "memory")
#define VMCNT0() asm volatile("s_waitcnt vmcnt(0)" ::: "memory")
#define LGKM0()  asm volatile("s_waitcnt lgkmcnt(0)" ::: "memory")

__device__ __forceinline__ ushort_t f2bf(float f) {
    union { float f; unsigned u; } v; v.f = f;
    unsigned r = v.u + 0x7FFFu + ((v.u >> 16) & 1u);
    return (ushort_t)(r >> 16);
}
__device__ __forceinline__ float bf2f(ushort_t h) {
    union { unsigned u; float f; } v; v.u = ((unsigned)h) << 16; return v.f;
}

// async 16B global->LDS copy; LDS dst is wave-uniform base (+lane*16 by HW)
__device__ __forceinline__ void async_cp16(const ushort_t* g, ushort_t* l) {
    __builtin_amdgcn_global_load_lds(
        (const __attribute__((address_space(1))) unsigned int*)g,
        (__attribute__((address_space(3))) unsigned int*)l, 16, 0, 0);
}

// ---------------- transpose+cast+GAP: x[b][c][p] f32 -> xt[b][p][c] bf16, GAP partials ----------------
__global__ void transpose_gap_kernel(const float* __restrict__ x, ushort_t* __restrict__ xt,
                                     float* __restrict__ gpart) {
    __shared__ float tile[32][33]; // [c][p], +1 pad
    int b = blockIdx.z, c0 = blockIdx.y * 32, p0 = blockIdx.x * 32;
    int t = threadIdx.x;
    int c = t >> 3, q = t & 7;         // c 0..31, q = p-quad 0..7
    f32x4 v = *(const f32x4*)(x + ((long)b * 256 + c0 + c) * 1024 + p0 + q * 4);
    tile[c][q * 4 + 0] = v[0];
    tile[c][q * 4 + 1] = v[1];
    tile[c][q * 4 + 2] = v[2];
    tile[c][q * 4 + 3] = v[3];
    float ps = v[0] + v[1] + v[2] + v[3];
    ps += __shfl_down(ps, 4, 8);
    ps += __shfl_down(ps, 2, 8);
    ps += __shfl_down(ps, 1, 8);
    if (q == 0) gpart[((long)b * 256 + c0 + c) * 32 + blockIdx.x] = ps;
    __syncthreads();
    int p = t >> 3, coff = (t & 7) * 4; // p 0..31, 4 consecutive c per lane
    u16x4 pk;
    #pragma unroll
    for (int i = 0; i < 4; ++i) pk[i] = f2bf(tile[coff + i][p]);
    *(u16x4*)(xt + ((long)b * 1024 + p0 + p) * 256 + c0 + coff) = pk;
}

// ---------------- router linear: r[b,e] = sigmoid(gap/1024 . rw[e] + rb[e]) ----------------
__global__ void router_linear_kernel(const float* __restrict__ gpart, const float* __restrict__ rw,
                                     const float* __restrict__ rb, float* __restrict__ r) {
    int be = blockIdx.x;          // b*8 + e
    int b = be >> 3, e = be & 7;
    int lane = threadIdx.x;       // 0..63
    float s = 0.f;
    #pragma unroll
    for (int i = 0; i < 4; ++i) {
        int c = lane + i * 64;
        const f32x4* gp = (const f32x4*)(gpart + ((long)b * 256 + c) * 32);
        float g = 0.f;
        #pragma unroll
        for (int j = 0; j < 8; ++j) { f32x4 v = gp[j]; g += (v[0] + v[1]) + (v[2] + v[3]); }
        s += g * rw[e * 256 + c];
    }
    #pragma unroll
    for (int off = 32; off; off >>= 1) s += __shfl_down(s, off, 64);
    if (lane == 0) r[be] = 1.f / (1.f + expf(-(s * (1.f / 1024.f) + rb[e])));
}

// ---------------- combine: ko[b][pos][g] = sum_e r[b,e]*w[e][g][pos], bf16 ----------------
__global__ __launch_bounds__(256, 2) void combine_kernel(const float* __restrict__ w,
                                                         const float* __restrict__ r,
                                                         ushort_t* __restrict__ ko) {
    __shared__ float wl[9216]; // 36864 B; aliased as outb after wv reg-loads
    ushort_t* outb = (ushort_t*)wl;
    const int t = threadIdx.x;
    const int g0 = blockIdx.x * 128;

    #pragma unroll
    for (int it = 0; it < 9; ++it) {
        int lin = it * 256 + t;
        int e = lin / 288, rem = lin - e * 288;
        f32x4 v = *(const f32x4*)(w + (long)e * 589824 + (long)g0 * 9 + rem * 4);
        *(f32x4*)(&wl[lin * 4]) = v;
    }
    __syncthreads();

    const int g = t & 127;
    const int half = t >> 7;   // wave-uniform
    float wv[8][9];
    #pragma unroll
    for (int e = 0; e < 8; ++e)
        #pragma unroll
        for (int p = 0; p < 9; ++p)
            wv[e][p] = wl[e * 1152 + g * 9 + p];
    __syncthreads(); // all wl reads done -> safe to alias as outb

    #pragma unroll
    for (int hb = 0; hb < 2; ++hb) { // 16 b per half-pass
        #pragma unroll
        for (int j = 0; j < 8; ++j) {
            int b16 = half * 8 + j;
            int b = hb * 16 + b16;
            float rv[8];
            #pragma unroll
            for (int e = 0; e < 8; ++e) rv[e] = r[b * 8 + e];
            #pragma unroll
            for (int p = 0; p < 9; ++p) {
                float s = 0.f;
                #pragma unroll
                for (int e = 0; e < 8; ++e) s += rv[e] * wv[e][p];
                outb[(b16 * 9 + p) * 128 + g] = f2bf(s);
            }
        }
        __syncthreads();
        #pragma unroll
        for (int it = 0; it < 9; ++it) {
            int idx = it * 256 + t;           // 0..2303
            int row = idx >> 4, off = idx & 15;
            int b16 = row / 9, p = row - b16 * 9;
            i32x4 v = *(i32x4*)(&outb[row * 128 + off * 8]);
            *(i32x4*)(ko + ((long)((hb * 16 + b16) * 9 + p)) * 65536 + g0 + off * 8) = v;
        }
        __syncthreads();
    }
}

// ---------------- implicit-GEMM conv 3x3 (pad 1), per-sample weights ----------------
// Round-11: 128-THREAD blocks (2 waves), wave tile 128m x 64n (mf 0..7, nf 0..3, 64 MFMA/iter).
// Rationale: at 64x64 tiles LDS-read cost (512 B/MFMA -> 1536 cy/CU/iter) exceeded MFMA
// (1241 cy) and the pipes serialize (measured 2950 ~ sum; all schedule tweaks neutral).
// 128x64 tile = 384 B/MFMA -> reads 1152 cy < MFMA 1241; 2 independent 2-wave blocks/CU
// (separate barrier domains) let one block's reads overlap the other's MFMAs.
// Schedule, LDS layouts, XOR swizzle, XCD mapping identical to the verified round-9 kernel;
// only the thread->work decomposition and staging loop indexing changed (stageA 8 cp16/thr
// -> counted wait vmcnt(8)). #pragma unroll 1 pins kc/pos rolled (round-5 I$ lesson).
// LDS 58880B -> 2 blocks/CU; 1 wave/SIMD -> launch_bounds(128,1) for VGPR headroom.
// MODE 0: out = bf16 relu(bn(conv)) [b][p][c];  MODE 1: out = f32 relu(bn(conv)+resid) [b][c][p]
template <int MODE>
__global__ __launch_bounds__(128, 1) void gemm_conv(
    const ushort_t* __restrict__ xin,   // [B][1024][256] bf16
    const ushort_t* __restrict__ kbank, // [B][9][256][256] bf16
    void* __restrict__ outp,
    const float* __restrict__ gam, const float* __restrict__ bet,
    const float* __restrict__ mu, const float* __restrict__ var,
    const ushort_t* __restrict__ residt) { // [B][1024][256] bf16 (MODE 1 only)
    __shared__ ushort_t smem[29440]; // ldsB: [0,13056) ; ldsA: 2 x 8192 at [13056, 29440)
    ushort_t* ldsB = smem;
    ushort_t* ldsA = smem + 13056;

    const int t = threadIdx.x;        // 0..127
    const int lane = t & 63;
    const int lane15 = lane & 15;
    const int quad = lane >> 4;
    const int wvi = t >> 6;           // wave 0/1
    // XCD swizzle decode (unchanged: 512 blocks)
    const int id = blockIdx.x;
    const int q  = id >> 3;           // mt + 2*nt + 16*(b>>3)
    const int mt = q & 1;
    const int nt = (q >> 1) & 7;
    const int b  = (id & 7) + ((q >> 4) << 3);
    const int h0 = nt * 4;
    const int p0 = nt * 128;
    const int nw0 = wvi * 64;         // wave covers all 128 m, 64 n
    const int wbase = t & ~63;

    f32x4 acc[8][4];
    #pragma unroll
    for (int i = 0; i < 8; ++i)
        #pragma unroll
        for (int j = 0; j < 4; ++j) acc[i][j] = 0.f;

    // pre-zero (once): border cols w'=0,33 for all 6 rows
    if (t < 96) {
        int rix = t >> 3, j = t & 7;
        int pi = (rix >> 1) * 34 + (rix & 1) * 33;
        i32x4 z = 0;
        *(i32x4*)(&ldsB[(pi * 8 + j) * 8]) = z;
    }
    // pre-zero invalid-h interior rows (boundary blocks only; skipped by stageB): 256 chunks, 2 rounds
    if (nt == 0) {
        i32x4 z = 0;
        *(i32x4*)(&ldsB[(8 + t) * 8]) = z;
        *(i32x4*)(&ldsB[(8 + 128 + t) * 8]) = z;
    }
    if (nt == 7) {
        i32x4 z = 0;
        *(i32x4*)(&ldsB[((5 * 34 + 1) * 8 + t) * 8]) = z;
        *(i32x4*)(&ldsB[((5 * 34 + 1) * 8 + 128 + t) * 8]) = z;
    }

    const long xbase = (long)b * 1024 * 256;
    const long kbase = (long)b * 9 * 65536;

    auto stageB = [&](int kc) {
        #pragma unroll
        for (int hh = 0; hh < 6; ++hh) {
            int hg = h0 + hh - 1;
            if (hg < 0 || hg >= 32) continue; // block-uniform
            #pragma unroll
            for (int rr = 0; rr < 2; ++rr) {
                int s = rr * 128 + t;
                int ww = s >> 3;
                int pi = hh * 34 + 1 + ww;
                int jd = (s & 7) ^ (pi & 7);
                async_cp16(xin + xbase + (long)(hg * 32 + ww) * 256 + kc * 64 + jd * 8,
                           ldsB + ((hh * 34 + 1) * 8 + rr * 128 + wbase) * 8);
            }
        }
    };
    auto stageA = [&](int kc, int pos, int buf) {
        const ushort_t* srcA = kbank + kbase + (long)pos * 65536 + (long)mt * 32768 + kc * 64;
        ushort_t* base = ldsA + buf * 8192;
        #pragma unroll
        for (int it = 0; it < 8; ++it) {
            int s = it * 128 + t;
            int row = s >> 3;                 // 0..127
            int k8 = (s & 7) ^ (row & 7);
            async_cp16(srcA + (long)row * 256 + k8 * 8, base + (it * 128 + wbase) * 8);
        }
    };

    stageB(0);
    stageA(0, 0, 0);
    __syncthreads(); // prologue: zero-fills + B tile + first A landed/published

    int par = 0;
    #pragma unroll 1
    for (int kc = 0; kc < 4; ++kc) {
        #pragma unroll 1
        for (int pos = 0; pos < 9; ++pos) {
            const bool last = (kc == 3 && pos == 8);
            if (!last) {
                int nk = kc, np = pos + 1;
                if (np == 9) { np = 0; ++nk; }
                stageA(nk, np, par ^ 1);   // 8 loads into buf[par^1]
                VMCNT8();                   // all-but-newest-8: buf[par] (+B at kc edge) landed
            } else {
                VMCNT0();
            }
            BAR();                          // bar_pub: stage data visible

            const int dh = pos / 3 - 1, dw = pos % 3 - 1;
            const ushort_t* ab = ldsA + par * 8192;
            bf16x8 af[2][8], bfr[2][4];
            #pragma unroll
            for (int kb = 0; kb < 2; ++kb) {
                int jk = kb * 4 + quad;
                #pragma unroll
                for (int mf = 0; mf < 8; ++mf) {
                    int row = mf * 16 + lane15;
                    af[kb][mf] = *(const bf16x8*)(ab + (row * 8 + (jk ^ (row & 7))) * 8);
                }
                #pragma unroll
                for (int nf = 0; nf < 4; ++nf) {
                    int n = nw0 + nf * 16 + lane15;
                    int pi = ((n >> 5) + 1 + dh) * 34 + (n & 31) + 1 + dw;
                    bfr[kb][nf] = *(const bf16x8*)(&ldsB[(pi * 8 + (jk ^ (pi & 7))) * 8]);
                }
            }
            LGKM0();                        // own ds_reads retired
            BAR();                          // bar_rd: both waves done reading buf[par]/ldsB

            if (pos == 8 && kc < 3) stageB(kc + 1); // safe after bar_rd; lands by next vmcnt+bar

            __builtin_amdgcn_s_setprio(1);
            #pragma unroll
            for (int kb = 0; kb < 2; ++kb)
                #pragma unroll
                for (int mf = 0; mf < 8; ++mf)
                    #pragma unroll
                    for (int nf = 0; nf < 4; ++nf)
                        acc[mf][nf] = __builtin_amdgcn_mfma_f32_16x16x32_bf16(af[kb][mf], bfr[kb][nf], acc[mf][nf], 0, 0, 0);
            __builtin_amdgcn_s_setprio(0);
            par ^= 1;
        }
    }

    // residual prefetch (MODE 1): bf16 from xt, 4 consecutive c per acc frag
    u16x4 rres[8][4];
    if (MODE == 1) {
        #pragma unroll
        for (int mf = 0; mf < 8; ++mf)
            #pragma unroll
            for (int nf = 0; nf < 4; ++nf) {
                int p = p0 + nw0 + nf * 16 + lane15;
                int cb = mt * 128 + mf * 16 + quad * 4;
                rres[mf][nf] = *(const u16x4*)(residt + ((long)b * 1024 + p) * 256 + cb);
            }
    }

    // BN scale/shift for this lane's 32 c_out values
    float sc[8][4], sh[8][4];
    #pragma unroll
    for (int mf = 0; mf < 8; ++mf)
        #pragma unroll
        for (int i = 0; i < 4; ++i) {
            int c = mt * 128 + mf * 16 + quad * 4 + i;
            float s = gam[c] * rsqrtf(var[c] + BN_EPS);
            sc[mf][i] = s;
            sh[mf][i] = bet[c] - mu[c] * s;
        }

    if (MODE == 0) {
        __syncthreads();
        ushort_t* ldsE = smem; // [128 p][EPAD c] = 34816 B
        #pragma unroll
        for (int mf = 0; mf < 8; ++mf)
            #pragma unroll
            for (int nf = 0; nf < 4; ++nf) {
                int pl = nw0 + nf * 16 + lane15;
                int cb = mf * 16 + quad * 4;
                u16x4 pk;
                #pragma unroll
                for (int i = 0; i < 4; ++i) {
                    float v = acc[mf][nf][i] * sc[mf][i] + sh[mf][i];
                    pk[i] = f2bf(fmaxf(v, 0.f));
                }
                *(u16x4*)(&ldsE[pl * EPAD + cb]) = pk;
            }
        __syncthreads();
        ushort_t* op = (ushort_t*)outp;
        #pragma unroll
        for (int it = 0; it < 16; ++it) {
            int s = t + it * 128;
            int row = s >> 4, l16 = s & 15;
            i32x4 v = *(i32x4*)(&ldsE[row * EPAD + l16 * 8]);
            *(i32x4*)(op + ((long)b * 1024 + p0 + row) * 256 + mt * 128 + l16 * 8) = v;
        }
    } else {
        float* op = (float*)outp;
        #pragma unroll
        for (int mf = 0; mf < 8; ++mf)
            #pragma unroll
            for (int nf = 0; nf < 4; ++nf) {
                int p = p0 + nw0 + nf * 16 + lane15;
                #pragma unroll
                for (int i = 0; i < 4; ++i) {
                    int c = mt * 128 + mf * 16 + quad * 4 + i;
                    float v = acc[mf][nf][i] * sc[mf][i] + sh[mf][i] + bf2f(rres[mf][nf][i]);
                    op[((long)b * 256 + c) * 1024 + p] = fmaxf(v, 0.f);
                }
            }
    }
}

extern "C" void kernel_launch(void* const* d_in, const int* in_sizes, int n_in,
                              void* d_out, int out_size, void* d_ws, size_t ws_size,
                              hipStream_t stream) {
    const float* x  = (const float*)d_in[0];
    const float* rw = (const float*)d_in[1];
    const float* rb = (const float*)d_in[2];
    const float* w1 = (const float*)d_in[3];
    const float* w2 = (const float*)d_in[4];
    const float* g1 = (const float*)d_in[5];
    const float* b1 = (const float*)d_in[6];
    const float* m1 = (const float*)d_in[7];
    const float* v1 = (const float*)d_in[8];
    const float* g2 = (const float*)d_in[9];
    const float* b2 = (const float*)d_in[10];
    const float* m2 = (const float*)d_in[11];
    const float* v2 = (const float*)d_in[12];

    // ws layout: r [0,1KB) | gpart [4096, +1MB) | xt | o1 | kbuf (reused for both layers)
    const size_t GP_OFF  = 4096;
    const size_t XT_OFF  = GP_OFF + (size_t)1048576;
    const size_t O1_OFF  = XT_OFF + (size_t)16777216;
    const size_t KB_OFF  = O1_OFF + (size_t)16777216;
    const size_t NEED    = KB_OFF + (size_t)32 * 9 * 65536 * 2;
    if (ws_size < NEED) return;

    char* ws = (char*)d_ws;
    float* r       = (float*)ws;
    float* gpart   = (float*)(ws + GP_OFF);
    ushort_t* xt   = (ushort_t*)(ws + XT_OFF);
    ushort_t* o1   = (ushort_t*)(ws + O1_OFF);
    ushort_t* kbuf = (ushort_t*)(ws + KB_OFF);

    transpose_gap_kernel<<<dim3(32, 8, 32), 256, 0, stream>>>(x, xt, gpart);
    router_linear_kernel<<<256, 64, 0, stream>>>(gpart, rw, rb, r);
    combine_kernel<<<dim3(512), 256, 0, stream>>>(w1, r, kbuf);
    gemm_conv<0><<<512, 128, 0, stream>>>(xt, kbuf, (void*)o1, g1, b1, m1, v1, nullptr);
    combine_kernel<<<dim3(512), 256, 0, stream>>>(w2, r, kbuf);
    gemm_conv<1><<<512, 128, 0, stream>>>(o1, kbuf, d_out, g2, b2, m2, v2, xt);
}

// Round 12
// 227.595 us; speedup vs baseline: 1.0933x; 1.0933x over previous
//
#include <hip/hip_runtime.h>

typedef unsigned short ushort_t;
typedef __attribute__((ext_vector_type(8))) __bf16 bf16x8;
typedef __attribute__((ext_vector_type(4))) float f32x4;
typedef __attribute__((ext_vector_type(4))) int i32x4;
typedef __attribute__((ext_vector_type(4))) unsigned short u16x4;

#define BN_EPS 1e-5f
#define EPAD 136  // epilogue [p][c] c-stride (272B row, 16B-aligned)

// counted waitcnt via inline asm (no builtin); memory clobber pins VMEM/LDS ops.
// barriers use the builtin (scheduler-aware, does NOT force a vmcnt drain).
#define BAR()    __builtin_amdgcn_s_barrier()
#define VMCNT0() asm volatile("s_waitcnt vmcnt(0)" ::: "memory")
#define LGKM0()  asm volatile("s_waitcnt lgkmcnt(0)" ::: "memory")

__device__ __forceinline__ ushort_t f2bf(float f) {
    union { float f; unsigned u; } v; v.f = f;
    unsigned r = v.u + 0x7FFFu + ((v.u >> 16) & 1u);
    return (ushort_t)(r >> 16);
}
__device__ __forceinline__ float bf2f(ushort_t h) {
    union { unsigned u; float f; } v; v.u = ((unsigned)h) << 16; return v.f;
}

// async 16B global->LDS copy; LDS dst is wave-uniform base (+lane*16 by HW)
__device__ __forceinline__ void async_cp16(const ushort_t* g, ushort_t* l) {
    __builtin_amdgcn_global_load_lds(
        (const __attribute__((address_space(1))) unsigned int*)g,
        (__attribute__((address_space(3))) unsigned int*)l, 16, 0, 0);
}

// ---------------- transpose+cast+GAP: x[b][c][p] f32 -> xt[b][p][c] bf16, GAP partials ----------------
__global__ void transpose_gap_kernel(const float* __restrict__ x, ushort_t* __restrict__ xt,
                                     float* __restrict__ gpart) {
    __shared__ float tile[32][33]; // [c][p], +1 pad
    int b = blockIdx.z, c0 = blockIdx.y * 32, p0 = blockIdx.x * 32;
    int t = threadIdx.x;
    int c = t >> 3, q = t & 7;         // c 0..31, q = p-quad 0..7
    f32x4 v = *(const f32x4*)(x + ((long)b * 256 + c0 + c) * 1024 + p0 + q * 4);
    tile[c][q * 4 + 0] = v[0];
    tile[c][q * 4 + 1] = v[1];
    tile[c][q * 4 + 2] = v[2];
    tile[c][q * 4 + 3] = v[3];
    float ps = v[0] + v[1] + v[2] + v[3];
    ps += __shfl_down(ps, 4, 8);
    ps += __shfl_down(ps, 2, 8);
    ps += __shfl_down(ps, 1, 8);
    if (q == 0) gpart[((long)b * 256 + c0 + c) * 32 + blockIdx.x] = ps;
    __syncthreads();
    int p = t >> 3, coff = (t & 7) * 4; // p 0..31, 4 consecutive c per lane
    u16x4 pk;
    #pragma unroll
    for (int i = 0; i < 4; ++i) pk[i] = f2bf(tile[coff + i][p]);
    *(u16x4*)(xt + ((long)b * 1024 + p0 + p) * 256 + c0 + coff) = pk;
}

// ---------------- router linear: r[b,e] = sigmoid(gap/1024 . rw[e] + rb[e]) ----------------
__global__ void router_linear_kernel(const float* __restrict__ gpart, const float* __restrict__ rw,
                                     const float* __restrict__ rb, float* __restrict__ r) {
    int be = blockIdx.x;          // b*8 + e
    int b = be >> 3, e = be & 7;
    int lane = threadIdx.x;       // 0..63
    float s = 0.f;
    #pragma unroll
    for (int i = 0; i < 4; ++i) {
        int c = lane + i * 64;
        const f32x4* gp = (const f32x4*)(gpart + ((long)b * 256 + c) * 32);
        float g = 0.f;
        #pragma unroll
        for (int j = 0; j < 8; ++j) { f32x4 v = gp[j]; g += (v[0] + v[1]) + (v[2] + v[3]); }
        s += g * rw[e * 256 + c];
    }
    #pragma unroll
    for (int off = 32; off; off >>= 1) s += __shfl_down(s, off, 64);
    if (lane == 0) r[be] = 1.f / (1.f + expf(-(s * (1.f / 1024.f) + rb[e])));
}

// ---------------- combine: ko[b][pos][g] = sum_e r[b,e]*w[e][g][pos], bf16 ----------------
__global__ __launch_bounds__(256, 2) void combine_kernel(const float* __restrict__ w,
                                                         const float* __restrict__ r,
                                                         ushort_t* __restrict__ ko) {
    __shared__ float wl[9216]; // 36864 B; aliased as outb after wv reg-loads
    ushort_t* outb = (ushort_t*)wl;
    const int t = threadIdx.x;
    const int g0 = blockIdx.x * 128;

    #pragma unroll
    for (int it = 0; it < 9; ++it) {
        int lin = it * 256 + t;
        int e = lin / 288, rem = lin - e * 288;
        f32x4 v = *(const f32x4*)(w + (long)e * 589824 + (long)g0 * 9 + rem * 4);
        *(f32x4*)(&wl[lin * 4]) = v;
    }
    __syncthreads();

    const int g = t & 127;
    const int half = t >> 7;   // wave-uniform
    float wv[8][9];
    #pragma unroll
    for (int e = 0; e < 8; ++e)
        #pragma unroll
        for (int p = 0; p < 9; ++p)
            wv[e][p] = wl[e * 1152 + g * 9 + p];
    __syncthreads(); // all wl reads done -> safe to alias as outb

    #pragma unroll
    for (int hb = 0; hb < 2; ++hb) { // 16 b per half-pass
        #pragma unroll
        for (int j = 0; j < 8; ++j) {
            int b16 = half * 8 + j;
            int b = hb * 16 + b16;
            float rv[8];
            #pragma unroll
            for (int e = 0; e < 8; ++e) rv[e] = r[b * 8 + e];
            #pragma unroll
            for (int p = 0; p < 9; ++p) {
                float s = 0.f;
                #pragma unroll
                for (int e = 0; e < 8; ++e) s += rv[e] * wv[e][p];
                outb[(b16 * 9 + p) * 128 + g] = f2bf(s);
            }
        }
        __syncthreads();
        #pragma unroll
        for (int it = 0; it < 9; ++it) {
            int idx = it * 256 + t;           // 0..2303
            int row = idx >> 4, off = idx & 15;
            int b16 = row / 9, p = row - b16 * 9;
            i32x4 v = *(i32x4*)(&outb[row * 128 + off * 8]);
            *(i32x4*)(ko + ((long)((hb * 16 + b16) * 9 + p)) * 65536 + g0 + off * 8) = v;
        }
        __syncthreads();
    }
}

// ---------------- implicit-GEMM conv 3x3 (pad 1), per-sample weights ----------------
// Round-12: round-9 geometry (256 thr, 4 waves, 64x64 wave tiles — round-11's 128-thr tile
// regressed: 1 wave/SIMD starved the scheduler). Schedule change: ONE barrier per iter and
// NO inline-asm between ds_reads and MFMAs — the compiler emits fine-grained lgkmcnt(N)
// so reads and MFMAs interleave (the explicit LGKM0+BAR wedge forced read-phase/MFMA-phase
// serialization: measured ~2950 cy/iter vs ~1536 LDS + ~310 MFMA floors).
// Iter: VMCNT0 (free: body > load latency); BAR (all stages landed + prior reads consumed);
//       stageA(next->buf^1) (overwrite legal by BAR); reads+MFMA straight-line.
// kc edge: LGKM0+BAR then stageB (ldsB single-buffered, 3x/kernel).
// LDS (16B chunks, XOR-swizzled, written only by global_load_lds):
//   ldsB: halo [6][34] rows x 8 k-chunks; slot(pi,j) = pi*8 + (j ^ (pi&7))
//   ldsA: 2 x (128 rows x 8 k-chunks); slot(row,j) = row*8 + (j ^ (row&7))
// MODE 0: out = bf16 relu(bn(conv)) [b][p][c];  MODE 1: out = f32 relu(bn(conv)+resid) [b][c][p]
template <int MODE>
__global__ __launch_bounds__(256, 2) void gemm_conv(
    const ushort_t* __restrict__ xin,   // [B][1024][256] bf16
    const ushort_t* __restrict__ kbank, // [B][9][256][256] bf16
    void* __restrict__ outp,
    const float* __restrict__ gam, const float* __restrict__ bet,
    const float* __restrict__ mu, const float* __restrict__ var,
    const ushort_t* __restrict__ residt) { // [B][1024][256] bf16 (MODE 1 only)
    __shared__ ushort_t smem[29440]; // ldsB: [0,13056) ; ldsA: 2 x 8192 at [13056, 29440)
    ushort_t* ldsB = smem;
    ushort_t* ldsA = smem + 13056;

    const int t = threadIdx.x;
    const int lane = t & 63;
    const int lane15 = lane & 15;
    const int quad = lane >> 4;
    const int wv = t >> 6;
    // XCD swizzle decode
    const int id = blockIdx.x;           // 0..511
    const int q  = id >> 3;              // mt + 2*nt + 16*(b>>3)
    const int mt = q & 1;
    const int nt = (q >> 1) & 7;
    const int b  = (id & 7) + ((q >> 4) << 3);
    const int h0 = nt * 4;
    const int p0 = nt * 128;
    const int mw0 = (wv >> 1) * 64;
    const int nw0 = (wv & 1) * 64;
    const int wbase = t & ~63;

    f32x4 acc[4][4];
    #pragma unroll
    for (int i = 0; i < 4; ++i)
        #pragma unroll
        for (int j = 0; j < 4; ++j) acc[i][j] = 0.f;

    // pre-zero (once; never overwritten): border cols w'=0,33 for all 6 rows
    if (t < 96) {
        int rix = t >> 3, j = t & 7;
        int pi = (rix >> 1) * 34 + (rix & 1) * 33;
        i32x4 z = 0;
        *(i32x4*)(&ldsB[(pi * 8 + j) * 8]) = z;
    }
    // pre-zero invalid-h interior rows (boundary blocks only; skipped by stageB)
    if (nt == 0) { i32x4 z = 0; *(i32x4*)(&ldsB[(8 + t) * 8]) = z; }                 // hh=0
    if (nt == 7) { i32x4 z = 0; *(i32x4*)(&ldsB[((5 * 34 + 1) * 8 + t) * 8]) = z; }  // hh=5

    const long xbase = (long)b * 1024 * 256;
    const long kbase = (long)b * 9 * 65536;

    auto stageB = [&](int kc) {
        #pragma unroll
        for (int hh = 0; hh < 6; ++hh) {
            int hg = h0 + hh - 1;
            if (hg < 0 || hg >= 32) continue; // block-uniform
            int ww = t >> 3;
            int pi = hh * 34 + 1 + ww;
            int jd = (t & 7) ^ (pi & 7);
            async_cp16(xin + xbase + (long)(hg * 32 + ww) * 256 + kc * 64 + jd * 8,
                       ldsB + ((hh * 34 + 1) * 8 + wbase) * 8);
        }
    };
    auto stageA = [&](int kc, int pos, int buf) {
        const ushort_t* srcA = kbank + kbase + (long)pos * 65536 + (long)mt * 32768 + kc * 64;
        ushort_t* base = ldsA + buf * 8192;
        #pragma unroll
        for (int it = 0; it < 4; ++it) {
            int s = it * 256 + t;
            int row = s >> 3;
            int k8 = (s & 7) ^ (row & 7);
            async_cp16(srcA + (long)row * 256 + k8 * 8, base + (it * 256 + wbase) * 8);
        }
    };

    stageB(0);
    stageA(0, 0, 0);
    __syncthreads(); // prologue: zero-fills + B tile + first A landed/published

    int par = 0;
    for (int kc = 0; kc < 4; ++kc) {
        for (int pos = 0; pos < 9; ++pos) {
            const bool last = (kc == 3 && pos == 8);
            VMCNT0();   // own stage(i-1) retired (~free: body exceeds load latency)
            BAR();      // all waves' stages landed; all prior reads of buf[par^1] consumed
            if (!last) {
                int nk = kc, np = pos + 1;
                if (np == 9) { np = 0; ++nk; }
                stageA(nk, np, par ^ 1);   // overwrite now-safe buffer; lands during body
            }

            const int dh = pos / 3 - 1, dw = pos % 3 - 1;
            const ushort_t* ab = ldsA + par * 8192;
            bf16x8 af[2][4], bfr[2][4];
            #pragma unroll
            for (int kb = 0; kb < 2; ++kb) {
                int jk = kb * 4 + quad;
                #pragma unroll
                for (int mf = 0; mf < 4; ++mf) {
                    int row = mw0 + mf * 16 + lane15;
                    af[kb][mf] = *(const bf16x8*)(ab + (row * 8 + (jk ^ (row & 7))) * 8);
                }
                #pragma unroll
                for (int nf = 0; nf < 4; ++nf) {
                    int n = nw0 + nf * 16 + lane15;
                    int pi = ((n >> 5) + 1 + dh) * 34 + (n & 31) + 1 + dw;
                    bfr[kb][nf] = *(const bf16x8*)(&ldsB[(pi * 8 + (jk ^ (pi & 7))) * 8]);
                }
            }
            // NO explicit lgkm/barrier here: compiler emits fine-grained lgkmcnt(N)
            // between reads and dependent MFMAs -> read/MFMA interleave.
            __builtin_amdgcn_s_setprio(1);
            #pragma unroll
            for (int kb = 0; kb < 2; ++kb)
                #pragma unroll
                for (int mf = 0; mf < 4; ++mf)
                    #pragma unroll
                    for (int nf = 0; nf < 4; ++nf)
                        acc[mf][nf] = __builtin_amdgcn_mfma_f32_16x16x32_bf16(af[kb][mf], bfr[kb][nf], acc[mf][nf], 0, 0, 0);
            __builtin_amdgcn_s_setprio(0);

            if (pos == 8 && kc < 3) {
                LGKM0();            // own ldsB reads consumed (free; MFMAs retired them)
                BAR();              // every wave done with this kc's B tile
                stageB(kc + 1);     // overwrite ldsB; lands by next iter's VMCNT0+BAR
            }
            par ^= 1;
        }
    }

    // residual prefetch (MODE 1): bf16 from xt, 4 consecutive c per acc frag
    u16x4 rres[4][4];
    if (MODE == 1) {
        #pragma unroll
        for (int mf = 0; mf < 4; ++mf)
            #pragma unroll
            for (int nf = 0; nf < 4; ++nf) {
                int p = p0 + nw0 + nf * 16 + lane15;
                int cb = mt * 128 + mw0 + mf * 16 + quad * 4;
                rres[mf][nf] = *(const u16x4*)(residt + ((long)b * 1024 + p) * 256 + cb);
            }
    }

    // BN scale/shift for this lane's 16 c_out values
    float sc[4][4], sh[4][4];
    #pragma unroll
    for (int mf = 0; mf < 4; ++mf)
        #pragma unroll
        for (int i = 0; i < 4; ++i) {
            int c = mt * 128 + mw0 + mf * 16 + quad * 4 + i;
            float s = gam[c] * rsqrtf(var[c] + BN_EPS);
            sc[mf][i] = s;
            sh[mf][i] = bet[c] - mu[c] * s;
        }

    if (MODE == 0) {
        __syncthreads();
        ushort_t* ldsE = smem; // [128 p][EPAD c]
        #pragma unroll
        for (int mf = 0; mf < 4; ++mf)
            #pragma unroll
            for (int nf = 0; nf < 4; ++nf) {
                int pl = nw0 + nf * 16 + lane15;
                int cb = mw0 + mf * 16 + quad * 4;
                u16x4 pk;
                #pragma unroll
                for (int i = 0; i < 4; ++i) {
                    float v = acc[mf][nf][i] * sc[mf][i] + sh[mf][i];
                    pk[i] = f2bf(fmaxf(v, 0.f));
                }
                *(u16x4*)(&ldsE[pl * EPAD + cb]) = pk;
            }
        __syncthreads();
        ushort_t* op = (ushort_t*)outp;
        #pragma unroll
        for (int it = 0; it < 8; ++it) {
            int s = t + it * 256;
            int row = s >> 4, l16 = s & 15;
            i32x4 v = *(i32x4*)(&ldsE[row * EPAD + l16 * 8]);
            *(i32x4*)(op + ((long)b * 1024 + p0 + row) * 256 + mt * 128 + l16 * 8) = v;
        }
    } else {
        float* op = (float*)outp;
        #pragma unroll
        for (int mf = 0; mf < 4; ++mf)
            #pragma unroll
            for (int nf = 0; nf < 4; ++nf) {
                int p = p0 + nw0 + nf * 16 + lane15;
                #pragma unroll
                for (int i = 0; i < 4; ++i) {
                    int c = mt * 128 + mw0 + mf * 16 + quad * 4 + i;
                    float v = acc[mf][nf][i] * sc[mf][i] + sh[mf][i] + bf2f(rres[mf][nf][i]);
                    op[((long)b * 256 + c) * 1024 + p] = fmaxf(v, 0.f);
                }
            }
    }
}

extern "C" void kernel_launch(void* const* d_in, const int* in_sizes, int n_in,
                              void* d_out, int out_size, void* d_ws, size_t ws_size,
                              hipStream_t stream) {
    const float* x  = (const float*)d_in[0];
    const float* rw = (const float*)d_in[1];
    const float* rb = (const float*)d_in[2];
    const float* w1 = (const float*)d_in[3];
    const float* w2 = (const float*)d_in[4];
    const float* g1 = (const float*)d_in[5];
    const float* b1 = (const float*)d_in[6];
    const float* m1 = (const float*)d_in[7];
    const float* v1 = (const float*)d_in[8];
    const float* g2 = (const float*)d_in[9];
    const float* b2 = (const float*)d_in[10];
    const float* m2 = (const float*)d_in[11];
    const float* v2 = (const float*)d_in[12];

    // ws layout: r [0,1KB) | gpart [4096, +1MB) | xt | o1 | kbuf (reused for both layers)
    const size_t GP_OFF  = 4096;
    const size_t XT_OFF  = GP_OFF + (size_t)1048576;
    const size_t O1_OFF  = XT_OFF + (size_t)16777216;
    const size_t KB_OFF  = O1_OFF + (size_t)16777216;
    const size_t NEED    = KB_OFF + (size_t)32 * 9 * 65536 * 2;
    if (ws_size < NEED) return;

    char* ws = (char*)d_ws;
    float* r       = (float*)ws;
    float* gpart   = (float*)(ws + GP_OFF);
    ushort_t* xt   = (ushort_t*)(ws + XT_OFF);
    ushort_t* o1   = (ushort_t*)(ws + O1_OFF);
    ushort_t* kbuf = (ushort_t*)(ws + KB_OFF);

    transpose_gap_kernel<<<dim3(32, 8, 32), 256, 0, stream>>>(x, xt, gpart);
    router_linear_kernel<<<256, 64, 0, stream>>>(gpart, rw, rb, r);
    combine_kernel<<<dim3(512), 256, 0, stream>>>(w1, r, kbuf);
    gemm_conv<0><<<512, 256, 0, stream>>>(xt, kbuf, (void*)o1, g1, b1, m1, v1, nullptr);
    combine_kernel<<<dim3(512), 256, 0, stream>>>(w2, r, kbuf);
    gemm_conv<1><<<512, 256, 0, stream>>>(o1, kbuf, d_out, g2, b2, m2, v2, xt);
}